// Round 6
// baseline (100.961 us; speedup 1.0000x reference)
//
#include <hip/hip_runtime.h>
#include <stdint.h>

using u16 = unsigned short;
using u32 = unsigned int;

typedef __attribute__((ext_vector_type(8))) short short8;
typedef __attribute__((ext_vector_type(4))) float f32x4;
typedef __attribute__((ext_vector_type(16))) float f32x16;

// ---------- helpers ----------
__device__ __forceinline__ u16 f2bf(float f) {
  u32 u = __builtin_bit_cast(u32, f);
  u = (u + 0x7fffu + ((u >> 16) & 1u)) >> 16;  // RNE
  return (u16)u;
}

__device__ __forceinline__ u32 cvtpk(float lo, float hi) {
  u32 r;
  asm("v_cvt_pk_bf16_f32 %0, %1, %2" : "=v"(r) : "v"(lo), "v"(hi));
  return r;
}

__device__ __forceinline__ short8 ld16(const u16* p) {
  uint4 v = *(const uint4*)p;
  union { uint4 u; short8 s; } c; c.u = v; return c.s;
}

__device__ __forceinline__ short8 ld16s(const u16* p) {  // LDS
  uint4 v = *(const uint4*)p;
  union { uint4 u; short8 s; } c; c.u = v; return c.s;
}

__device__ __forceinline__ void gload_lds16(const void* g, void* l) {
  __builtin_amdgcn_global_load_lds(
      (const __attribute__((address_space(1))) void*)g,
      (__attribute__((address_space(3))) void*)l, 16, 0, 0);
}

__device__ __forceinline__ f32x16 mfma32(short8 a, short8 b, f32x16 c) {
  return __builtin_amdgcn_mfma_f32_32x32x16_bf16(a, b, c, 0, 0, 0);
}

// ---------- kernel 1: fp32 -> bf16 elementwise (vectorized x4) ----------
__global__ __launch_bounds__(256) void k_f32_to_bf16(const float* __restrict__ in,
                                                     u16* __restrict__ out, int n4) {
  int i = blockIdx.x * 256 + threadIdx.x;
  if (i >= n4) return;
  float4 v = ((const float4*)in)[i];
  ushort4 o;
  o.x = f2bf(v.x); o.y = f2bf(v.y); o.z = f2bf(v.z); o.w = f2bf(v.w);
  ((ushort4*)out)[i] = o;
}

// ---------- kernel 2: fp32 [R][C] -> bf16 [C][R] (transpose + convert) ----------
__global__ __launch_bounds__(256) void k_transpose_bf16(const float* __restrict__ in,
                                                        u16* __restrict__ out, int R, int C) {
  __shared__ float tile[32][33];
  int c0 = blockIdx.x * 32, r0 = blockIdx.y * 32;
  int tx = threadIdx.x & 31, ty = threadIdx.x >> 5;
#pragma unroll
  for (int i = 0; i < 4; ++i) {
    int r = ty + 8 * i;
    tile[r][tx] = in[(size_t)(r0 + r) * C + c0 + tx];
  }
  __syncthreads();
#pragma unroll
  for (int i = 0; i < 4; ++i) {
    int r = ty + 8 * i;
    out[(size_t)(c0 + r) * R + r0 + tx] = f2bf(tile[tx][r]);
  }
}

// ---------- GEMM: C[M][N] = A[M][K] * B[K][N], A row-major bf16, BT = B^T [N][K] bf16 ----------
// 128x128 tile, BK=64, 2-phase double-buffered LDS pipeline (see round-5 comment).
// EPI 0: scatter qkv into MFMA-fragment-packed layouts; EPI 1: fp32 out.
template <int EPI>
__global__ __launch_bounds__(256, 2) void k_gemm(
    const u16* __restrict__ A, const u16* __restrict__ BT, int M, int N, int K,
    u16* __restrict__ qb, u16* __restrict__ kb, u16* __restrict__ vbT,
    float* __restrict__ out) {
  __shared__ __align__(16) u16 As[2][128 * 64];
  __shared__ __align__(16) u16 Bs[2][128 * 64];
  const int t = threadIdx.x;
  const int l = t & 63;
  const int wid = t >> 6;
  const int wr = wid >> 1, wc = wid & 1;
  const int lr = l & 15, lg = l >> 4;
  const int cpx = (int)gridDim.x >> 3;
  const int nb = (blockIdx.x & 7) * cpx + ((int)blockIdx.x >> 3);
  const int ntile = N >> 7;
  const int mt = nb / ntile, nt = nb % ntile;
  const int m0 = mt << 7, n0 = nt << 7;

  f32x4 zero = {0.f, 0.f, 0.f, 0.f};
  f32x4 acc[4][4];
#pragma unroll
  for (int i = 0; i < 4; ++i)
#pragma unroll
    for (int j = 0; j < 4; ++j) acc[i][j] = zero;

  const u16* Ab = A + (size_t)m0 * K;
  const u16* Bb = BT + (size_t)n0 * K;
  const int nkt = K >> 6;

  auto STAGE = [&](int kt, int bsel) {
    const u16* Ak = Ab + kt * 64;
    const u16* Bk = Bb + kt * 64;
#pragma unroll
    for (int i = 0; i < 4; ++i) {
      int o16 = i * 256 + t;
      int row = o16 >> 3, c = o16 & 7;
      int sc = c ^ (row & 7);
      gload_lds16(Ak + (size_t)row * K + sc * 8, &As[bsel][o16 * 8]);
    }
#pragma unroll
    for (int i = 0; i < 4; ++i) {
      int o16 = i * 256 + t;
      int row = o16 >> 3, c = o16 & 7;
      int sc = c ^ (row & 7);
      gload_lds16(Bk + (size_t)row * K + sc * 8, &Bs[bsel][o16 * 8]);
    }
  };

  STAGE(0, 0);
  asm volatile("s_waitcnt vmcnt(0)" ::: "memory");
  __builtin_amdgcn_s_barrier();

  for (int kt = 0; kt < nkt; ++kt) {
    const int cur = kt & 1;
    if (kt + 1 < nkt) STAGE(kt + 1, cur ^ 1);  // loads in flight during compute
#pragma unroll
    for (int ks = 0; ks < 2; ++ks) {
      short8 a[4], b[4];
#pragma unroll
      for (int mi = 0; mi < 4; ++mi) {
        int row = wr * 64 + mi * 16 + lr;
        int c = (ks * 4 + lg) ^ (row & 7);
        a[mi] = ld16(&As[cur][(row * 8 + c) * 8]);
      }
#pragma unroll
      for (int ni = 0; ni < 4; ++ni) {
        int row = wc * 64 + ni * 16 + lr;
        int c = (ks * 4 + lg) ^ (row & 7);
        b[ni] = ld16(&Bs[cur][(row * 8 + c) * 8]);
      }
#pragma unroll
      for (int mi = 0; mi < 4; ++mi)
#pragma unroll
        for (int ni = 0; ni < 4; ++ni)
          acc[mi][ni] = __builtin_amdgcn_mfma_f32_16x16x32_bf16(a[mi], b[ni], acc[mi][ni], 0, 0, 0);
    }
    asm volatile("s_waitcnt vmcnt(0)" ::: "memory");
    __builtin_amdgcn_s_barrier();
    asm volatile("" ::: "memory");
  }

#pragma unroll
  for (int mi = 0; mi < 4; ++mi) {
#pragma unroll
    for (int ni = 0; ni < 4; ++ni) {
#pragma unroll
      for (int r = 0; r < 4; ++r) {
        float v = acc[mi][ni][r];
        int m = m0 + wr * 64 + mi * 16 + 4 * lg + r;
        int n = n0 + wc * 64 + ni * 16 + lr;
        if (EPI == 0) {
          int bb = m >> 11, s = m & 2047;
          int tau = s >> 5, i32e = s & 31;
          if (n < 1024) {
            int h = n >> 6, d = n & 63;
            int kc = d >> 4, hi2 = (d >> 3) & 1, e = d & 7;
            // fold SCALE (1/8) * log2(e): softmax runs in exp2 domain
            qb[((size_t)(bb * 16 + h)) * 131072 +
               (size_t)((tau * 4 + kc) * 64 + (hi2 << 5 | i32e)) * 8 + e] = f2bf(v * 0.18033688f);
          } else if (n < 1280) {
            int g = (n - 1024) >> 6, d = n & 63;
            int kc = d >> 4, hi2 = (d >> 3) & 1, e = d & 7;
            kb[((size_t)(bb * 4 + g)) * 131072 +
               (size_t)((tau * 4 + kc) * 64 + (hi2 << 5 | i32e)) * 8 + e] = f2bf(v);
          } else {
            int g = (n - 1280) >> 6, dT = n & 63;
            int c = (s >> 4) & 1, hi2 = (s >> 3) & 1, e = s & 7;
            int dd = dT >> 5, i32v = dT & 31;
            vbT[((size_t)(bb * 4 + g)) * 131072 +
                (size_t)(((tau * 2 + dd) * 2 + c) * 64 + (hi2 << 5 | i32v)) * 8 + e] = f2bf(v);
          }
        } else {
          out[(size_t)m * N + n] = v;
        }
      }
    }
  }
}

// ---------- attention: block-cooperative causal GQA flash ----------
// Block = 128 contiguous q-rows of one (b,h); 4 waves (32 rows each) iterate the SAME
// kv-blocks in lockstep. K/V staged once per block into double-buffered LDS via
// global_load_lds (packed layout is block-contiguous: 8KB linear per 64-kv block).
// L1 traffic 4x lower than private streaming; fragment reads come from LDS pipe.
// blockIdx -> (bh, T) mapped so round-robin dispatch pairs T with 15-T per CU
// (complementary durations -> ~uniform CU busy time). Perf heuristic only.
__global__ __launch_bounds__(256, 2) void k_attn(const u16* __restrict__ qbuf,
                                                 const u16* __restrict__ kbuf,
                                                 const u16* __restrict__ vbuf,
                                                 u16* __restrict__ attn) {
  __shared__ __align__(16) u16 Ks[2][4096];  // 8 KB per buffer
  __shared__ __align__(16) u16 Vs[2][4096];
  const int t = threadIdx.x;
  const int l = t & 63, wid = t >> 6;
  const int i32 = l & 31, hi = l >> 5;
  const int id = blockIdx.x;
  const int bh = id >> 4;                                  // 0..31
  const int T = (id & 15) ^ (((id >> 8) & 1) ? 15 : 0);    // pair T with 15-T across halves
  const int b = bh >> 4, h = bh & 15, g = h >> 2;          // rep=4
  const int q0 = T * 128 + wid * 32;                       // this wave's 32 rows
  const int nblkw = (q0 >> 6) + 1;                         // wave's causal kv-block count
  const int nmax = 2 * T + 2;                              // block's kv-block count

  const u16* qp = qbuf + ((size_t)(b * 16 + h)) * 131072;
  const u16* kp = kbuf + ((size_t)(b * 4 + g)) * 131072;
  const u16* vp = vbuf + ((size_t)(b * 4 + g)) * 131072;

  // Q fragments (B operand): packed, lane-contiguous
  short8 qf[4];
#pragma unroll
  for (int kc = 0; kc < 4; ++kc)
    qf[kc] = ld16(qp + ((size_t)((q0 >> 5) * 4 + kc) * 64 + l) * 8);

  f32x16 z16 = {0.f, 0.f, 0.f, 0.f, 0.f, 0.f, 0.f, 0.f,
                0.f, 0.f, 0.f, 0.f, 0.f, 0.f, 0.f, 0.f};
  f32x16 o[2];  // O^T; reg R -> d = dd*32 + (R&3)+8*(R>>2)+4*hi, col i32
  o[0] = z16; o[1] = z16;
  float mrun = -1e30f, lsum = 0.f;

  // stage kv-block n (8 KB K + 8 KB V, both linear) into LDS buffer bsel
  auto STAGE = [&](int n, int bsel) {
    const u16* kblk = kp + (size_t)n * 4096;
    const u16* vblk = vp + (size_t)n * 4096;
    gload_lds16(kblk + t * 8, &Ks[bsel][t * 8]);
    gload_lds16(kblk + (256 + t) * 8, &Ks[bsel][(256 + t) * 8]);
    gload_lds16(vblk + t * 8, &Vs[bsel][t * 8]);
    gload_lds16(vblk + (256 + t) * 8, &Vs[bsel][(256 + t) * 8]);
  };

  STAGE(0, 0);
  asm volatile("s_waitcnt vmcnt(0)" ::: "memory");
  __builtin_amdgcn_s_barrier();

  int cur = 0;
  for (int n = 0; n < nmax; ++n) {
    if (n + 1 < nmax) STAGE(n + 1, cur ^ 1);  // prefetch flies during compute
    if (n < nblkw) {
      const int kv0 = n * 64;
      // K fragments from LDS
      short8 kf[2][4];
#pragma unroll
      for (int mf = 0; mf < 2; ++mf)
#pragma unroll
        for (int kc = 0; kc < 4; ++kc)
          kf[mf][kc] = ld16s(&Ks[cur][((mf * 4 + kc) * 64 + l) * 8]);

      // S^T = K * Q^T
      f32x16 sc[2];
      __builtin_amdgcn_s_setprio(1);
      sc[0] = mfma32(kf[0][0], qf[0], z16);
      sc[1] = mfma32(kf[1][0], qf[0], z16);
#pragma unroll
      for (int kc = 1; kc < 4; ++kc) {
        sc[0] = mfma32(kf[0][kc], qf[kc], sc[0]);
        sc[1] = mfma32(kf[1][kc], qf[kc], sc[1]);
      }
      __builtin_amdgcn_s_setprio(0);

      if (n == nblkw - 1) {  // diagonal block: mask j > i
        const int iloc = (q0 - kv0) + i32;
#pragma unroll
        for (int mf = 0; mf < 2; ++mf)
#pragma unroll
          for (int R = 0; R < 16; ++R) {
            int j = 32 * mf + (R & 3) + 8 * (R >> 2) + 4 * hi;
            if (j > iloc) sc[mf][R] = -1e30f;
          }
      }

      // row max: tree over own 32 regs, cross-half via permlane32_swap (VALU)
      float mq[8];
#pragma unroll
      for (int k = 0; k < 8; ++k) {
        int mf = k >> 2, b4 = (k & 3) * 4;
        mq[k] = fmaxf(fmaxf(sc[mf][b4], sc[mf][b4 + 1]), fmaxf(sc[mf][b4 + 2], sc[mf][b4 + 3]));
      }
      float mx = fmaxf(fmaxf(fmaxf(mq[0], mq[1]), fmaxf(mq[2], mq[3])),
                       fmaxf(fmaxf(mq[4], mq[5]), fmaxf(mq[6], mq[7])));
      {
        u32 mu = __builtin_bit_cast(u32, mx);
        auto r = __builtin_amdgcn_permlane32_swap(mu, mu, false, false);
        mx = fmaxf(__builtin_bit_cast(float, (u32)r[0]), __builtin_bit_cast(float, (u32)r[1]));
      }
      // defer-max (T13)
      if (!__all(mx - mrun <= 8.0f)) {
        float mnew = fmaxf(mrun, mx);
        float alpha = __builtin_amdgcn_exp2f(mrun - mnew);
        mrun = mnew;
        lsum *= alpha;
#pragma unroll
        for (int dd = 0; dd < 2; ++dd)
#pragma unroll
          for (int R = 0; R < 16; ++R) o[dd][R] *= alpha;
      }

      // P = exp2(S - m) in place; per-lane partial sum
      float s0 = 0.f, s1 = 0.f, s2 = 0.f, s3 = 0.f;
#pragma unroll
      for (int mf = 0; mf < 2; ++mf)
#pragma unroll
        for (int R = 0; R < 16; R += 4) {
          float p0 = __builtin_amdgcn_exp2f(sc[mf][R] - mrun);
          float p1 = __builtin_amdgcn_exp2f(sc[mf][R + 1] - mrun);
          float p2 = __builtin_amdgcn_exp2f(sc[mf][R + 2] - mrun);
          float p3 = __builtin_amdgcn_exp2f(sc[mf][R + 3] - mrun);
          sc[mf][R] = p0; sc[mf][R + 1] = p1; sc[mf][R + 2] = p2; sc[mf][R + 3] = p3;
          s0 += p0; s1 += p1; s2 += p2; s3 += p3;
        }
      lsum += (s0 + s1) + (s2 + s3);

      // pack P -> bf16 B-fragments via cvt_pk + permlane32_swap (T12)
      short8 pb[2][2];
#pragma unroll
      for (int mf = 0; mf < 2; ++mf)
#pragma unroll
        for (int c = 0; c < 2; ++c) {
          union { u32 w[4]; short8 s8; } U;
#pragma unroll
          for (int q = 0; q < 2; ++q) {
            u32 wa = cvtpk(sc[mf][8 * c + 2 * q], sc[mf][8 * c + 2 * q + 1]);
            u32 wb = cvtpk(sc[mf][8 * c + 4 + 2 * q], sc[mf][8 * c + 4 + 2 * q + 1]);
            auto r = __builtin_amdgcn_permlane32_swap(wa, wb, false, false);
            U.w[q] = (u32)r[0];
            U.w[2 + q] = (u32)r[1];
          }
          pb[mf][c] = U.s8;
        }

      // V fragments from LDS
      short8 vf[2][2][2];
#pragma unroll
      for (int mf = 0; mf < 2; ++mf)
#pragma unroll
        for (int dd = 0; dd < 2; ++dd)
#pragma unroll
          for (int c = 0; c < 2; ++c)
            vf[dd][mf][c] = ld16s(&Vs[cur][((4 * mf + 2 * dd + c) * 64 + l) * 8]);

      // O^T += V^T * P^T
      __builtin_amdgcn_s_setprio(1);
#pragma unroll
      for (int mf = 0; mf < 2; ++mf)
#pragma unroll
        for (int c = 0; c < 2; ++c) {
          o[0] = mfma32(vf[0][mf][c], pb[mf][c], o[0]);
          o[1] = mfma32(vf[1][mf][c], pb[mf][c], o[1]);
        }
      __builtin_amdgcn_s_setprio(0);
    }
    asm volatile("s_waitcnt vmcnt(0)" ::: "memory");  // staged buffer complete
    __builtin_amdgcn_s_barrier();
    cur ^= 1;
  }

  // cross-half sum, normalize, write attn[b][q0+i][h*64+d] (bf16)
  float tot;
  {
    u32 su = __builtin_bit_cast(u32, lsum);
    auto r = __builtin_amdgcn_permlane32_swap(su, su, false, false);
    tot = __builtin_bit_cast(float, (u32)r[0]) + __builtin_bit_cast(float, (u32)r[1]);
  }
  float inv = 1.f / tot;
  u16* ao = attn + ((size_t)(b * 2048 + q0)) * 1024 + h * 64;
#pragma unroll
  for (int dd = 0; dd < 2; ++dd) {
#pragma unroll
    for (int R = 0; R < 16; R += 2) {
      int d = dd * 32 + (R & 3) + 8 * (R >> 2) + 4 * hi;
      u32 w = cvtpk(o[dd][R] * inv, o[dd][R + 1] * inv);
      *(u32*)(ao + (size_t)i32 * 1024 + d) = w;
    }
  }
}

// ---------- launch ----------
extern "C" void kernel_launch(void* const* d_in, const int* in_sizes, int n_in,
                              void* d_out, int out_size, void* d_ws, size_t ws_size,
                              hipStream_t stream) {
  const float* hs = (const float*)d_in[0];    // [2,2048,1024]
  const float* wqkv = (const float*)d_in[1];  // [1024,1536]
  const float* wo = (const float*)d_in[2];    // [1024,1024]
  float* out = (float*)d_out;                 // [2,2048,1024] fp32
  u16* ws = (u16*)d_ws;

  u16* hsb = ws;                   // 4096*1024
  u16* wqkvT = hsb + 4194304;      // 1536*1024
  u16* woT = wqkvT + 1572864;      // 1024*1024
  u16* qb = woT + 1048576;         // packed Q: 32 * 131072
  u16* kb = qb + 4194304;          // packed K: 8 * 131072
  u16* vb = kb + 1048576;          // packed V: 8 * 131072
  u16* attn = vb + 1048576;        // 4096*1024
  (void)in_sizes; (void)n_in; (void)out_size; (void)ws_size;

  k_f32_to_bf16<<<4096, 256, 0, stream>>>(hs, hsb, 1048576);
  k_transpose_bf16<<<dim3(48, 32), 256, 0, stream>>>(wqkv, wqkvT, 1024, 1536);
  k_transpose_bf16<<<dim3(32, 32), 256, 0, stream>>>(wo, woT, 1024, 1024);
  k_gemm<0><<<384, 256, 0, stream>>>(hsb, wqkvT, 4096, 1536, 1024, qb, kb, vb, nullptr);
  k_attn<<<512, 256, 0, stream>>>(qb, kb, vb, attn);
  k_gemm<1><<<256, 256, 0, stream>>>(attn, woT, 4096, 1024, 1024, nullptr, nullptr, nullptr, out);
}